// Round 1
// baseline (416.175 us; speedup 1.0000x reference)
//
#include <hip/hip_runtime.h>

typedef __attribute__((ext_vector_type(8))) short short8;
typedef __attribute__((ext_vector_type(4))) float f32x4;

// fp32 -> bf16 bits, round-to-nearest-even
__device__ __forceinline__ short f2bf(float f) {
    unsigned u = __builtin_bit_cast(unsigned, f);
    u += 0x7fffu + ((u >> 16) & 1u);
    return (short)(u >> 16);
}

// Kernel 1: W_eff = sum_r s_r * W_r, stored TRANSPOSED as bf16: WT[n*128+k].
__global__ void weff_kernel(const float* __restrict__ W,
                            const float* __restrict__ S,
                            short* __restrict__ WT) {
    int idx = blockIdx.x * 256 + threadIdx.x;   // 0..16383 == k*128 + n
    int k = idx >> 7;
    int n = idx & 127;
    float acc = 0.f;
#pragma unroll
    for (int r = 0; r < 8; ++r) acc += S[r] * W[r * 16384 + idx];
    WT[n * 128 + k] = f2bf(acc);
}

// Kernel 2: C[M,128] = A[M,128] @ W_eff[128,128], bf16 MFMA, fp32 accumulate.
// Block: 256 threads = 4 waves; each wave does 16 rows x 128 cols, full K=128.
#define BSTRIDE 136   // 128 + 8 bf16 pad: keeps 16B alignment, 2-way (free) LDS banking

__global__ __launch_bounds__(256, 4) void gemm_kernel(const float* __restrict__ A,
                                                      const short* __restrict__ WT,
                                                      float* __restrict__ C,
                                                      int N) {
    __shared__ __align__(16) short Bs[128 * BSTRIDE];

    int tid = threadIdx.x;
    // Stage W_eff^T (bf16) into padded LDS: 2048 x 16B chunks, coalesced.
#pragma unroll
    for (int it = 0; it < 8; ++it) {
        int chunk = it * 256 + tid;            // 0..2047
        int n  = chunk >> 4;                   // row of WT (output col)
        int kc = chunk & 15;                   // which 8-element k chunk
        *(short8*)&Bs[n * BSTRIDE + kc * 8] = ((const short8*)WT)[chunk];
    }
    __syncthreads();

    int wave = tid >> 6;
    int lane = tid & 63;
    int quad = lane >> 4;
    int r16  = lane & 15;

    long m0   = (long)blockIdx.x * 64 + wave * 16;
    long rowA = m0 + r16;
    long rowAc = rowA < N ? rowA : (long)(N - 1);   // clamp: junk rows never stored
    const float* arow = A + rowAc * 128;

    f32x4 acc[8];
#pragma unroll
    for (int t = 0; t < 8; ++t) acc[t] = (f32x4)(0.f);

#pragma unroll
    for (int kk = 0; kk < 4; ++kk) {
        int k = kk * 32 + quad * 8;            // A frag: A[m=r16][k..k+7]
        float4 p = *(const float4*)(arow + k);
        float4 q = *(const float4*)(arow + k + 4);
        short8 afrag;
        afrag[0] = f2bf(p.x); afrag[1] = f2bf(p.y);
        afrag[2] = f2bf(p.z); afrag[3] = f2bf(p.w);
        afrag[4] = f2bf(q.x); afrag[5] = f2bf(q.y);
        afrag[6] = f2bf(q.z); afrag[7] = f2bf(q.w);
#pragma unroll
        for (int t = 0; t < 8; ++t) {
            // B frag: B[k..k+7][n = t*16 + r16] == WT[(t*16+r16)][k..k+7]
            short8 bfrag = *(const short8*)&Bs[(t * 16 + r16) * BSTRIDE + k];
            acc[t] = __builtin_amdgcn_mfma_f32_16x16x32_bf16(afrag, bfrag, acc[t], 0, 0, 0);
        }
    }

    // C/D layout: col = lane&15 (+16*t), row = quad*4 + reg
#pragma unroll
    for (int reg = 0; reg < 4; ++reg) {
        long row = m0 + quad * 4 + reg;
        if (row < N) {
            float* crow = C + row * 128;
#pragma unroll
            for (int t = 0; t < 8; ++t) crow[t * 16 + r16] = acc[t][reg];
        }
    }
}

extern "C" void kernel_launch(void* const* d_in, const int* in_sizes, int n_in,
                              void* d_out, int out_size, void* d_ws, size_t ws_size,
                              hipStream_t stream) {
    const float* inputs = (const float*)d_in[0];     // [N,128] fp32
    const float* W      = (const float*)d_in[1];     // [8,128,128] fp32
    const float* S      = (const float*)d_in[2];     // [8,1] fp32
    float* out = (float*)d_out;                      // [N,128] fp32
    short* WT  = (short*)d_ws;                       // [128,128] bf16 (W_eff^T)

    int N = in_sizes[0] / 128;

    weff_kernel<<<64, 256, 0, stream>>>(W, S, WT);
    int grid = (N + 63) / 64;
    gemm_kernel<<<grid, 256, 0, stream>>>(inputs, WT, out, N);
}